// Round 8
// baseline (138.338 us; speedup 1.0000x reference)
//
#include <hip/hip_runtime.h>
#include <math.h>

// Problem constants (from reference: B=1024, N=4096, fp32).
#define BATCH    1024
#define NPTS     4096
#define THREADS  256
#define WAVES    4
#define NV       (NPTS / 4)        // float4 per row = 1024
#define ITERS    (NV / THREADS)    // 4 float4 iterations per thread
#define NSTREAM  7
#define NACC     23
#define RPAD     264               // reduction row stride (256+8): conflict-free

typedef float fx4 __attribute__((ext_vector_type(4)));

// Accumulator layout (23 floats):
//  0      : sw        = sum w
//  1..3   : mw[i]     = sum m_i w
//  4..6   : yw[i]     = sum y_i w
//  7..12  : Mw sym    = (00,01,02,11,12,22)
// 13..21  : MY[i][j]  row-major
// 22     : yy        = sum (y.y) w

// R7 bug: per-STREAM phases broke product alignment (w[n]*m[n]*y[n] needs the
// same n on all streams). Correct form: a single per-BLOCK phase applied
// identically to all 7 streams — exact (sum is order-invariant), while still
// decorrelating the 1024 blocks' sweep cursors mod 16 KB (channel-camping
// hypothesis, cross-block component).
__global__ __launch_bounds__(THREADS) void locblock_fused(
    const float* __restrict__ m,   // (B,3,N)
    const float* __restrict__ y,   // (B,3,N)
    const float* __restrict__ w,   // (B,1,N)
    float* __restrict__ out)       // Qn (B*169) | scales (B) | offsets (B)
{
    const int b    = blockIdx.x;
    const int tid  = threadIdx.x;
    const int lane = tid & 63;
    const int wave = tid >> 6;

    const size_t mb = (size_t)b * 3 * NPTS;
    const float* rows[NSTREAM] = {
        m + mb + 0 * NPTS, m + mb + 1 * NPTS, m + mb + 2 * NPTS,
        y + mb + 0 * NPTS, y + mb + 1 * NPTS, y + mb + 2 * NPTS,
        w + (size_t)b * NPTS
    };

    // Per-block phase (float4 units), same for all streams. 41 is odd ->
    // phases cover all residues mod 1024; 41*16B = 656B stride between
    // consecutive blocks' cursors decorrelates channel-select address bits.
    const int ph = (b * 41) & (NV - 1);

    float acc[NACC];
#pragma unroll
    for (int i = 0; i < NACC; ++i) acc[i] = 0.f;

    auto accum = [&](float wv, float m0v, float m1v, float m2v,
                     float y0v, float y1v, float y2v) {
        float wm0 = wv * m0v, wm1 = wv * m1v, wm2 = wv * m2v;
        acc[0]  += wv;
        acc[1]  += wm0;        acc[2]  += wm1;        acc[3]  += wm2;
        acc[4]  += wv * y0v;   acc[5]  += wv * y1v;   acc[6]  += wv * y2v;
        acc[7]  += wm0 * m0v;  acc[8]  += wm0 * m1v;  acc[9]  += wm0 * m2v;
        acc[10] += wm1 * m1v;  acc[11] += wm1 * m2v;  acc[12] += wm2 * m2v;
        acc[13] += wm0 * y0v;  acc[14] += wm0 * y1v;  acc[15] += wm0 * y2v;
        acc[16] += wm1 * y0v;  acc[17] += wm1 * y1v;  acc[18] += wm1 * y2v;
        acc[19] += wm2 * y0v;  acc[20] += wm2 * y1v;  acc[21] += wm2 * y2v;
        acc[22] += wv * (y0v * y0v + y1v * y1v + y2v * y2v);
    };

    for (int it = 0; it < ITERS; ++it) {
        const int v = (tid + it * THREADS + ph) & (NV - 1);  // same n for all streams
        fx4 d[NSTREAM];
#pragma unroll
        for (int s = 0; s < NSTREAM; ++s) {
            d[s] = *(const fx4*)(rows[s] + 4 * v);
        }
#pragma unroll
        for (int e = 0; e < 4; ++e) {
            accum(d[6][e], d[0][e], d[1][e], d[2][e], d[3][e], d[4][e], d[5][e]);
        }
    }

    // ---- Reduction: LDS fold (256 -> 64 lanes) + wave-0 butterfly ----
    __shared__ float red_lds[NACC * RPAD];
    __shared__ float sums[NACC];
    __shared__ float sqred[WAVES];
    __shared__ float scale_s;

#pragma unroll
    for (int i = 0; i < NACC; ++i) red_lds[i * RPAD + tid] = acc[i];
    __syncthreads();

    if (wave == 0) {
        float part[NACC];
#pragma unroll
        for (int i = 0; i < NACC; ++i) {
            const float* row = &red_lds[i * RPAD + lane];
            part[i] = row[0] + row[64] + row[128] + row[192];
        }
#pragma unroll
        for (int i = 0; i < NACC; ++i) {
            float v = part[i];
            v += __shfl_xor(v, 32, 64);
            v += __shfl_xor(v, 16, 64);
            v += __shfl_xor(v, 8, 64);
            v += __shfl_xor(v, 4, 64);
            v += __shfl_xor(v, 2, 64);
            v += __shfl_xor(v, 1, 64);
            part[i] = v;
        }
        if (lane == 0) {
#pragma unroll
            for (int i = 0; i < NACC; ++i) sums[i] = part[i];
        }
    }
    __syncthreads();

    // ---- Epilogue: assemble Q (one entry per thread), normalize, store ----
    float qv = 0.f;
    if (tid < 169) {
        const int r = tid / 13, c = tid % 13;
        const float* mwv = &sums[1];
        const float* ywv = &sums[4];
        auto Mwf = [&](int i, int j) -> float {
            if (i > j) { int t = i; i = j; j = t; }
            int idx = (i == 0) ? j : ((i == 1) ? (j + 2) : 5);
            return sums[7 + idx];
        };
        auto MYf = [&](int i, int j) -> float { return sums[13 + i * 3 + j]; };

        if (r == 0) {
            if (c == 0)            qv = 0.f;
            else if (c <= 9)       qv = -MYf((c - 1) / 3, (c - 1) % 3);   // Qch
            else                   qv = ywv[c - 10];
        } else if (c == 0) {
            if (r <= 9)            qv = -MYf((r - 1) / 3, (r - 1) % 3);   // Qch
            else                   qv = ywv[r - 10];
        } else if (r <= 9 && c <= 9) {                                    // Qcc
            int a = r - 1, d = c - 1;
            int i = a / 3, k = a % 3, j = d / 3, l = d % 3;
            qv = (k == l) ? Mwf(i, j) : 0.f;
        } else if (r <= 9) {                                              // Qct
            int a = r - 1, i = a / 3, k = a % 3, l = c - 10;
            qv = (k == l) ? -mwv[i] : 0.f;
        } else if (c <= 9) {                                              // Qct^T
            int a = c - 1, i = a / 3, k = a % 3, l = r - 10;
            qv = (k == l) ? -mwv[i] : 0.f;
        } else {                                                          // Qtt
            qv = (r == c) ? sums[0] : 0.f;
        }
    }

    // Block-wide sum of squares -> scale.
    float sq = (tid < 169) ? qv * qv : 0.f;
    sq += __shfl_xor(sq, 32, 64);
    sq += __shfl_xor(sq, 16, 64);
    sq += __shfl_xor(sq, 8, 64);
    sq += __shfl_xor(sq, 4, 64);
    sq += __shfl_xor(sq, 2, 64);
    sq += __shfl_xor(sq, 1, 64);
    if (lane == 0) sqred[wave] = sq;
    __syncthreads();
    if (tid == 0) {
        scale_s = sqrtf(sqred[0] + sqred[1] + sqred[2] + sqred[3]);
    }
    __syncthreads();

    const float inv_scale = 1.0f / scale_s;
    if (tid < 169) {
        out[(size_t)b * 169 + tid] = qv * inv_scale;
    }
    if (tid == 0) {
        out[(size_t)BATCH * 169 + b]         = scale_s;   // scales
        out[(size_t)BATCH * 169 + BATCH + b] = sums[22];  // offsets (yy)
    }
}

extern "C" void kernel_launch(void* const* d_in, const int* in_sizes, int n_in,
                              void* d_out, int out_size, void* d_ws, size_t ws_size,
                              hipStream_t stream) {
    const float* m = (const float*)d_in[0];  // keypoints_3D_src (B,3,N)
    const float* y = (const float*)d_in[1];  // keypoints_3D_trg (B,3,N)
    const float* w = (const float*)d_in[2];  // weights (B,1,N)
    float* out = (float*)d_out;
    locblock_fused<<<BATCH, THREADS, 0, stream>>>(m, y, w, out);
}